// Round 1
// baseline (181.314 us; speedup 1.0000x reference)
//
#include <hip/hip_runtime.h>

#define BATCH_N   16384
#define NFIELDS   20
#define FIELD_DIM 50000
#define ROW_W     32   // emb_table row width in floats (EMBED_DIM * (ORDER-1))

// 8 threads per batch row; thread t owns dims [4t, 4t+4).
// Threads 0..3 cover the order-2 half (dims 0..15) -> e2 per dim.
// Threads 4..7 cover the order-3 half (dims 16..31) -> e3 per dim.
// Unified DP (a1,a2,a3) runs on all threads; select a2 vs a3 at the end.
__global__ __launch_bounds__(256) void hofm_kernel(
    const int*   __restrict__ x,
    const float* __restrict__ emb,
    const float* __restrict__ lin,
    const float* __restrict__ bias,
    float*       __restrict__ out)
{
    const int tid = blockIdx.x * blockDim.x + threadIdx.x;
    const int row = tid >> 3;   // batch row
    const int t   = tid & 7;    // sub-lane within row
    if (row >= BATCH_N) return;

    const int* xr = x + row * NFIELDS;

    float a1[4] = {0.f, 0.f, 0.f, 0.f};
    float a2[4] = {0.f, 0.f, 0.f, 0.f};
    float a3[4] = {0.f, 0.f, 0.f, 0.f};
    float linsum = 0.f;

    #pragma unroll
    for (int f = 0; f < NFIELDS; ++f) {
        const int idx = xr[f] + f * FIELD_DIM;
        const float4 v = *(const float4*)(emb + (size_t)idx * ROW_W + t * 4);
        if ((f & 7) == t) linsum += lin[idx];   // distribute lin gathers over lanes
        float vv[4] = {v.x, v.y, v.z, v.w};
        #pragma unroll
        for (int d = 0; d < 4; ++d) {
            a3[d] += vv[d] * a2[d];
            a2[d] += vv[d] * a1[d];
            a1[d] += vv[d];
        }
    }

    float partial = (t < 4) ? (a2[0] + a2[1] + a2[2] + a2[3])
                            : (a3[0] + a3[1] + a3[2] + a3[3]);
    partial += linsum;

    // reduce across the 8 lanes of this row (width=8 confines to the group)
    partial += __shfl_down(partial, 4, 8);
    partial += __shfl_down(partial, 2, 8);
    partial += __shfl_down(partial, 1, 8);

    if (t == 0) out[row] = partial + bias[0];
}

extern "C" void kernel_launch(void* const* d_in, const int* in_sizes, int n_in,
                              void* d_out, int out_size, void* d_ws, size_t ws_size,
                              hipStream_t stream) {
    const int*   x    = (const int*)  d_in[0];
    const float* emb  = (const float*)d_in[1];
    const float* lin  = (const float*)d_in[2];
    const float* bias = (const float*)d_in[3];
    float*       out  = (float*)d_out;

    const int total_threads = BATCH_N * 8;
    const int block = 256;
    const int grid  = (total_threads + block - 1) / block;
    hofm_kernel<<<grid, block, 0, stream>>>(x, emb, lin, bias, out);
}

// Round 2
// 175.497 us; speedup vs baseline: 1.0331x; 1.0331x over previous
//
#include <hip/hip_runtime.h>

#define BATCH_N   16384
#define NFIELDS   20
#define FIELD_DIM 50000
#define ROW_W     32   // emb row width in floats
#define FPG       5    // fields per quarter-group

// 32 threads per batch row:
//   d = t & 7  : dim group, owns dims [4d, 4d+4) of the 32-float emb row
//   q = t >> 3 : field quarter, owns fields [5q, 5q+5)
// Each thread runs the e1/e2/e3 DP over its 5 fields, then a 2-level
// shfl_xor combine tree (q^1, then q^2) merges the field quarters:
//   e3 = e3a+e3b + e2a*e1b + e1a*e2b ; e2 = e2a+e2b + e1a*e1b ; e1 = e1a+e1b
// Dims 0..15 (threads d<4) contribute e2; dims 16..31 (d>=4) contribute e3.
__global__ __launch_bounds__(256) void hofm_kernel(
    const int*   __restrict__ x,
    const float* __restrict__ emb,
    const float* __restrict__ lin,
    const float* __restrict__ bias,
    float*       __restrict__ out)
{
    const int tid = blockIdx.x * blockDim.x + threadIdx.x;
    const int row = tid >> 5;
    const int t   = tid & 31;
    const int d   = t & 7;
    const int q   = t >> 3;
    if (row >= BATCH_N) return;

    const int* xr = x + row * NFIELDS + q * FPG;

    float a1[4] = {0.f, 0.f, 0.f, 0.f};
    float a2[4] = {0.f, 0.f, 0.f, 0.f};
    float a3[4] = {0.f, 0.f, 0.f, 0.f};
    float linsum = 0.f;

    #pragma unroll
    for (int j = 0; j < FPG; ++j) {
        const int f   = q * FPG + j;
        const int idx = xr[j] + f * FIELD_DIM;
        const float4 v = *(const float4*)(emb + (size_t)idx * ROW_W + d * 4);
        if (j == d) linsum += lin[idx];   // lanes d=0..4 of each quarter: 1 lin gather
        float vv[4] = {v.x, v.y, v.z, v.w};
        #pragma unroll
        for (int k = 0; k < 4; ++k) {
            a3[k] += vv[k] * a2[k];
            a2[k] += vv[k] * a1[k];
            a1[k] += vv[k];
        }
    }

    // combine field quarters: level 1 merges q pairs (0,1),(2,3); level 2 merges halves
    #pragma unroll
    for (int lvl = 0; lvl < 2; ++lvl) {
        const int mask = 8 << lvl;   // lane xor 8, then 16
        #pragma unroll
        for (int k = 0; k < 4; ++k) {
            const float p1 = __shfl_xor(a1[k], mask, 32);
            const float p2 = __shfl_xor(a2[k], mask, 32);
            const float p3 = __shfl_xor(a3[k], mask, 32);
            a3[k] = a3[k] + p3 + a2[k] * p1 + a1[k] * p2;
            a2[k] = a2[k] + p2 + a1[k] * p1;
            a1[k] = a1[k] + p1;
        }
    }

    const float espsum = (d < 4) ? (a2[0] + a2[1] + a2[2] + a2[3])
                                 : (a3[0] + a3[1] + a3[2] + a3[3]);
    // every quarter now holds identical esp values; count it once (q==0)
    float partial = ((q == 0) ? espsum : 0.f) + linsum;

    // reduce across the 32 lanes of this row
    partial += __shfl_down(partial, 16, 32);
    partial += __shfl_down(partial,  8, 32);
    partial += __shfl_down(partial,  4, 32);
    partial += __shfl_down(partial,  2, 32);
    partial += __shfl_down(partial,  1, 32);

    if (t == 0) out[row] = partial + bias[0];
}

extern "C" void kernel_launch(void* const* d_in, const int* in_sizes, int n_in,
                              void* d_out, int out_size, void* d_ws, size_t ws_size,
                              hipStream_t stream) {
    const int*   x    = (const int*)  d_in[0];
    const float* emb  = (const float*)d_in[1];
    const float* lin  = (const float*)d_in[2];
    const float* bias = (const float*)d_in[3];
    float*       out  = (float*)d_out;

    const int total_threads = BATCH_N * 32;
    const int block = 256;
    const int grid  = (total_threads + block - 1) / block;
    hofm_kernel<<<grid, block, 0, stream>>>(x, emb, lin, bias, out);
}

// Round 3
// 170.526 us; speedup vs baseline: 1.0633x; 1.0292x over previous
//
#include <hip/hip_runtime.h>

#define BATCH_N   16384
#define NFIELDS   20
#define FIELD_DIM 50000
#define ROW_W     32   // emb row width in floats
#define FPG       5    // fields per quarter-group

typedef float f32x4 __attribute__((ext_vector_type(4)));

// 32 threads per batch row:
//   d = t & 7  : dim group, owns dims [4d, 4d+4) of the 32-float emb row
//   q = t >> 3 : field quarter, owns fields [5q, 5q+5)
// Per-thread e1/e2/e3 DP over 5 fields, then 2-level shfl_xor combine across
// field quarters (ESP merge rule), then 8-lane dim reduction.
// Entire problem (524288 threads) is co-resident: one full-occupancy pass.
// Gathers are nontemporal: zero L1 reuse (42 MB random / 32 KiB L1).
__global__ __launch_bounds__(256) void hofm_kernel(
    const int*   __restrict__ x,
    const float* __restrict__ emb,
    const float* __restrict__ lin,
    const float* __restrict__ bias,
    float*       __restrict__ out)
{
    const int tid = blockIdx.x * blockDim.x + threadIdx.x;
    const int row = tid >> 5;
    const int t   = tid & 31;
    const int d   = t & 7;
    const int q   = t >> 3;
    if (row >= BATCH_N) return;

    const int* xr = x + row * NFIELDS + q * FPG;

    // load all 5 indices first (broadcast across the 8 d-lanes of a quarter)
    int idx[FPG];
    #pragma unroll
    for (int j = 0; j < FPG; ++j)
        idx[j] = xr[j] + (q * FPG + j) * FIELD_DIM;

    // issue all gathers (nontemporal), then do the DP math
    f32x4 v[FPG];
    #pragma unroll
    for (int j = 0; j < FPG; ++j)
        v[j] = __builtin_nontemporal_load(
                   (const f32x4*)(emb + (size_t)idx[j] * ROW_W + d * 4));

    float linsum = 0.f;
    if (d < FPG)
        linsum = __builtin_nontemporal_load(lin + idx[d]);

    float a1[4] = {0.f, 0.f, 0.f, 0.f};
    float a2[4] = {0.f, 0.f, 0.f, 0.f};
    float a3[4] = {0.f, 0.f, 0.f, 0.f};

    #pragma unroll
    for (int j = 0; j < FPG; ++j) {
        #pragma unroll
        for (int k = 0; k < 4; ++k) {
            const float vv = v[j][k];
            a3[k] += vv * a2[k];
            a2[k] += vv * a1[k];
            a1[k] += vv;
        }
    }

    // combine field quarters: lane xor 8, then xor 16
    #pragma unroll
    for (int lvl = 0; lvl < 2; ++lvl) {
        const int mask = 8 << lvl;
        #pragma unroll
        for (int k = 0; k < 4; ++k) {
            const float p1 = __shfl_xor(a1[k], mask, 32);
            const float p2 = __shfl_xor(a2[k], mask, 32);
            const float p3 = __shfl_xor(a3[k], mask, 32);
            a3[k] = a3[k] + p3 + a2[k] * p1 + a1[k] * p2;
            a2[k] = a2[k] + p2 + a1[k] * p1;
            a1[k] = a1[k] + p1;
        }
    }

    const float espsum = (d < 4) ? (a2[0] + a2[1] + a2[2] + a2[3])
                                 : (a3[0] + a3[1] + a3[2] + a3[3]);
    // esp values are replicated across quarters post-combine; count once
    float partial = ((q == 0) ? espsum : 0.f) + linsum;

    // reduce across the 32 lanes of this row
    partial += __shfl_down(partial, 16, 32);
    partial += __shfl_down(partial,  8, 32);
    partial += __shfl_down(partial,  4, 32);
    partial += __shfl_down(partial,  2, 32);
    partial += __shfl_down(partial,  1, 32);

    if (t == 0) out[row] = partial + bias[0];
}

extern "C" void kernel_launch(void* const* d_in, const int* in_sizes, int n_in,
                              void* d_out, int out_size, void* d_ws, size_t ws_size,
                              hipStream_t stream) {
    const int*   x    = (const int*)  d_in[0];
    const float* emb  = (const float*)d_in[1];
    const float* lin  = (const float*)d_in[2];
    const float* bias = (const float*)d_in[3];
    float*       out  = (float*)d_out;

    const int total_threads = BATCH_N * 32;
    const int block = 256;
    const int grid  = (total_threads + block - 1) / block;
    hofm_kernel<<<grid, block, 0, stream>>>(x, emb, lin, bias, out);
}